// Round 6
// baseline (314.312 us; speedup 1.0000x reference)
//
#include <hip/hip_runtime.h>

#define SEQ 512
#define BATCH 8192
#define HDIM 10
#define LOG2E  1.44269504088896340736f
#define LOG2E2 2.88539008177792681472f   // 2*log2(e)

typedef float f2 __attribute__((ext_vector_type(2)));

__device__ __forceinline__ float bperm(int addr_bytes, float v) {
    return __int_as_float(__builtin_amdgcn_ds_bpermute(addr_bytes, __float_as_int(v)));
}
__device__ __forceinline__ float fexp2(float x) { return __builtin_amdgcn_exp2f(x); }
__device__ __forceinline__ float frcp(float x)  { return __builtin_amdgcn_rcpf(x); }
__device__ __forceinline__ f2 mk2(float a, float b) { f2 r; r.x = a; r.y = b; return r; }
__device__ __forceinline__ f2 fma2(f2 a, f2 b, f2 c) { return __builtin_elementwise_fma(a, b, c); }

#define PIN(v)  asm volatile("" : "+v"(v))

// Unit-per-lane LSTM, 16 lanes per batch element (10 useful), 2 waves/SIMD.
// Iteration t computes L0[t+1] and L1[t] (software pipeline).
// This round: maximum single-wave ILP — BOTH dot phases issued first
// (8 independent pk_fma chains), then BOTH activations interleaved with
// cross-layer paired reciprocals (4 rcp for 8 gate denoms + 1 for the two
// tanh(c)), then all 20 h-broadcast bperms batched at iteration end.
// Ping-pong unroll x2 eliminates pipeline-register copies.
__global__ __launch_bounds__(256, 2) void lstm2_fc_kernel(
    const float* __restrict__ x,
    const float* __restrict__ w_ih0, const float* __restrict__ w_hh0,
    const float* __restrict__ b_ih0, const float* __restrict__ b_hh0,
    const float* __restrict__ w_ih1, const float* __restrict__ w_hh1,
    const float* __restrict__ b_ih1, const float* __restrict__ b_hh1,
    const float* __restrict__ fc_w, const float* __restrict__ fc_b,
    float* __restrict__ out)
{
    const int tid    = threadIdx.x;
    const int lane16 = tid & 15;
    const int b      = blockIdx.x * 16 + (tid >> 4);
    const int gbase  = tid & 48;                 // 16-lane group base in wave
    const int u      = (lane16 < HDIM) ? lane16 : 9;   // clamp dummy lanes

    // ---- loop-invariant weights, packed + prescaled ----
    f2 wi0p[4], wh0p[4][5], wi1p[4][5], wh1p[4][5];
    float bb0[4], bb1[4];
    #pragma unroll
    for (int g = 0; g < 4; ++g) {
        const int r   = g * 10 + u;
        const float m = (g == 2) ? LOG2E2 : -LOG2E;
        wi0p[g] = mk2(m * w_ih0[r * 2 + 0], m * w_ih0[r * 2 + 1]);
        bb0[g]  = m * (b_ih0[r] + b_hh0[r]);
        bb1[g]  = m * (b_ih1[r] + b_hh1[r]);
        #pragma unroll
        for (int k = 0; k < 5; ++k) {
            wh0p[g][k] = mk2(m * w_hh0[r * HDIM + 2 * k], m * w_hh0[r * HDIM + 2 * k + 1]);
            wi1p[g][k] = mk2(m * w_ih1[r * HDIM + 2 * k], m * w_ih1[r * HDIM + 2 * k + 1]);
            wh1p[g][k] = mk2(m * w_hh1[r * HDIM + 2 * k], m * w_hh1[r * HDIM + 2 * k + 1]);
        }
    }
    #pragma unroll
    for (int g = 0; g < 4; ++g) {
        PIN(wi0p[g]); PIN(bb0[g]); PIN(bb1[g]);
        #pragma unroll
        for (int k = 0; k < 5; ++k) { PIN(wh0p[g][k]); PIN(wi1p[g][k]); PIN(wh1p[g][k]); }
    }

    // ---- h-broadcast addresses ----
    int hb[HDIM];
    #pragma unroll
    for (int j = 0; j < HDIM; ++j) hb[j] = (gbase + j) * 4;

    // ---- state (ping-pong h1) ----
    f2 h1a[5], h1b[5], h2p[5];
    #pragma unroll
    for (int k = 0; k < 5; ++k) { h1a[k] = mk2(0.f, 0.f); h1b[k] = mk2(0.f, 0.f); h2p[k] = mk2(0.f, 0.f); }
    float c1 = 0.0f, c2 = 0.0f;

    // ---- prologue: L0 at t=0 (h1 = 0 -> only x terms) -> h1a ----
    {
        const f2 x0 = *reinterpret_cast<const f2*>(x + (size_t)b * 2);
        float z[4];
        #pragma unroll
        for (int g = 0; g < 4; ++g) {
            const f2 a = wi0p[g] * x0;
            z[g] = (a.x + a.y) + bb0[g];
        }
        const float d0 = 1.0f + fexp2(z[0]);
        const float d1 = 1.0f + fexp2(z[1]);
        const float d2 = 1.0f + fexp2(z[2]);
        const float d3 = 1.0f + fexp2(z[3]);
        const float p0 = frcp(d0 * d1);
        const float p1 = frcp(d2 * d3);
        const float i0 = d1 * p0;
        const float g0 = fmaf(-2.0f, d3 * p1, 1.0f);
        const float o0 = d2 * p1;
        c1 = i0 * g0;                                  // c was 0
        const float e0 = 1.0f + fexp2(LOG2E2 * c1);
        const float th = fmaf(-2.0f, frcp(e0), 1.0f);
        const float h1o = o0 * th;
        #pragma unroll
        for (int k = 0; k < 5; ++k)
            h1a[k] = mk2(bperm(hb[2 * k], h1o), bperm(hb[2 * k + 1], h1o));
    }

    f2 xv = *reinterpret_cast<const f2*>(x + ((size_t)1 * BATCH + b) * 2);

    // One pipelined step: computes L0[T+1] (reads H1IN, xv=x[T+1]) and
    // L1[T] (reads H1IN, h2p); writes h1[T+1] -> H1OUT, h2[T] -> h2p.
#define STEP(H1IN, H1OUT, T)                                                   \
    {                                                                          \
        const int t_ = (T);                                                    \
        const int tn = (t_ + 2 < SEQ) ? (t_ + 2) : (SEQ - 1);                  \
        const f2 xnext =                                                       \
            *reinterpret_cast<const f2*>(x + ((size_t)tn * BATCH + b) * 2);    \
        float z0[4], z1[4];                                                    \
        _Pragma("unroll")                                                      \
        for (int g = 0; g < 4; ++g) {                                          \
            f2 a = wi0p[g] * xv;                                               \
            _Pragma("unroll")                                                  \
            for (int k = 0; k < 5; ++k) a = fma2(wh0p[g][k], H1IN[k], a);      \
            z0[g] = (a.x + a.y) + bb0[g];                                      \
        }                                                                      \
        _Pragma("unroll")                                                      \
        for (int g = 0; g < 4; ++g) {                                          \
            f2 a = wi1p[g][0] * H1IN[0];                                       \
            _Pragma("unroll")                                                  \
            for (int k = 1; k < 5; ++k) a = fma2(wi1p[g][k], H1IN[k], a);      \
            _Pragma("unroll")                                                  \
            for (int k = 0; k < 5; ++k) a = fma2(wh1p[g][k], h2p[k], a);       \
            z1[g] = (a.x + a.y) + bb1[g];                                      \
        }                                                                      \
        const float d0 = 1.0f + fexp2(z0[0]);                                  \
        const float d1 = 1.0f + fexp2(z0[1]);                                  \
        const float d2 = 1.0f + fexp2(z0[2]);                                  \
        const float d3 = 1.0f + fexp2(z0[3]);                                  \
        const float d4 = 1.0f + fexp2(z1[0]);                                  \
        const float d5 = 1.0f + fexp2(z1[1]);                                  \
        const float d6 = 1.0f + fexp2(z1[2]);                                  \
        const float d7 = 1.0f + fexp2(z1[3]);                                  \
        const float p0 = frcp(d0 * d1);                                        \
        const float p1 = frcp(d2 * d3);                                        \
        const float p2 = frcp(d4 * d5);                                        \
        const float p3 = frcp(d6 * d7);                                        \
        const float i0 = d1 * p0, f0 = d0 * p0;                                \
        const float g0 = fmaf(-2.0f, d3 * p1, 1.0f), o0 = d2 * p1;             \
        const float i1 = d5 * p2, f1 = d4 * p2;                                \
        const float g1 = fmaf(-2.0f, d7 * p3, 1.0f), o1 = d6 * p3;             \
        c1 = fmaf(f0, c1, i0 * g0);                                            \
        c2 = fmaf(f1, c2, i1 * g1);                                            \
        const float e0 = 1.0f + fexp2(LOG2E2 * c1);                            \
        const float e1 = 1.0f + fexp2(LOG2E2 * c2);                            \
        const float pc = frcp(e0 * e1);                                        \
        const float th0 = fmaf(-2.0f, e1 * pc, 1.0f);                          \
        const float th1 = fmaf(-2.0f, e0 * pc, 1.0f);                          \
        const float h1o = o0 * th0;                                            \
        const float h2o = o1 * th1;                                            \
        _Pragma("unroll")                                                      \
        for (int k = 0; k < 5; ++k) {                                          \
            H1OUT[k] = mk2(bperm(hb[2 * k], h1o), bperm(hb[2 * k + 1], h1o));  \
            h2p[k]   = mk2(bperm(hb[2 * k], h2o), bperm(hb[2 * k + 1], h2o));  \
        }                                                                      \
        xv = xnext;                                                            \
    }

    // main loop: 511 pipelined steps = 255 ping-pong pairs + 1
    for (int i = 0; i < 255; ++i) {
        STEP(h1a, h1b, 2 * i);
        STEP(h1b, h1a, 2 * i + 1);
    }
    STEP(h1a, h1b, 510);
#undef STEP

    // ---- epilogue: L1 at t = SEQ-1 (reads h1b = h1[511], h2p = h2[510]) ----
    {
        float z1[4];
        #pragma unroll
        for (int g = 0; g < 4; ++g) {
            f2 a = wi1p[g][0] * h1b[0];
            #pragma unroll
            for (int k = 1; k < 5; ++k) a = fma2(wi1p[g][k], h1b[k], a);
            #pragma unroll
            for (int k = 0; k < 5; ++k) a = fma2(wh1p[g][k], h2p[k], a);
            z1[g] = (a.x + a.y) + bb1[g];
        }
        const float d4 = 1.0f + fexp2(z1[0]);
        const float d5 = 1.0f + fexp2(z1[1]);
        const float d6 = 1.0f + fexp2(z1[2]);
        const float d7 = 1.0f + fexp2(z1[3]);
        const float p2 = frcp(d4 * d5);
        const float p3 = frcp(d6 * d7);
        const float i1 = d5 * p2, f1 = d4 * p2;
        const float g1 = fmaf(-2.0f, d7 * p3, 1.0f), o1 = d6 * p3;
        c2 = fmaf(f1, c2, i1 * g1);
        const float e1 = 1.0f + fexp2(LOG2E2 * c2);
        const float th1 = fmaf(-2.0f, frcp(e1), 1.0f);
        const float h2o = o1 * th1;
        #pragma unroll
        for (int k = 0; k < 5; ++k)
            h2p[k] = mk2(bperm(hb[2 * k], h2o), bperm(hb[2 * k + 1], h2o));
    }

    // ---- FC: out[b][k] = fc_b[k] + sum_j fc_w[k][j] * h2[j] ----
    if (lane16 < 2) {
        float acc = fc_b[lane16];
        #pragma unroll
        for (int k = 0; k < 5; ++k) {
            acc = fmaf(fc_w[lane16 * HDIM + 2 * k],     h2p[k].x, acc);
            acc = fmaf(fc_w[lane16 * HDIM + 2 * k + 1], h2p[k].y, acc);
        }
        out[(size_t)b * 2 + lane16] = acc;
    }
}

extern "C" void kernel_launch(void* const* d_in, const int* in_sizes, int n_in,
                              void* d_out, int out_size, void* d_ws, size_t ws_size,
                              hipStream_t stream) {
    const float* x     = (const float*)d_in[0];
    const float* w_ih0 = (const float*)d_in[1];
    const float* w_hh0 = (const float*)d_in[2];
    const float* b_ih0 = (const float*)d_in[3];
    const float* b_hh0 = (const float*)d_in[4];
    const float* w_ih1 = (const float*)d_in[5];
    const float* w_hh1 = (const float*)d_in[6];
    const float* b_ih1 = (const float*)d_in[7];
    const float* b_hh1 = (const float*)d_in[8];
    const float* fc_w  = (const float*)d_in[9];
    const float* fc_b  = (const float*)d_in[10];
    float* out = (float*)d_out;

    const int threads = 256;                  // 16 batch elements per block
    const int blocks  = BATCH / 16;           // 512 blocks -> 2 blocks/CU
    lstm2_fc_kernel<<<blocks, threads, 0, stream>>>(
        x, w_ih0, w_hh0, b_ih0, b_hh0,
        w_ih1, w_hh1, b_ih1, b_hh1, fc_w, fc_b, out);
}